// Round 1
// baseline (43.827 us; speedup 1.0000x reference)
//
#include <hip/hip_runtime.h>
#include <math.h>

// Problem: x, inp : float32 [8, 15, 512, 512]
// out[b] = -(1/0.001) * sum over (t,x,y) of (inp-x)^2 where isfinite(inp), else 0
// Pure HBM-bound reduction: 251.7 MB read, 32 B written.

constexpr int N_B = 8;
constexpr long long N_PER_BATCH = 15LL * 512 * 512;       // 3,932,160 (divisible by 4)
constexpr int BLOCKS_PER_BATCH = 256;
constexpr int THREADS = 256;
constexpr float NEG_INV_NOISE = -1000.0f;                  // -1/0.001

__device__ __forceinline__ float wave_reduce_add(float v) {
    // full 64-lane wave reduction
    #pragma unroll
    for (int off = 32; off > 0; off >>= 1)
        v += __shfl_down(v, off, 64);
    return v;
}

__global__ __launch_bounds__(THREADS)
void nlpobs_partial(const float* __restrict__ x,
                    const float* __restrict__ inp,
                    float* __restrict__ partial) {
    const int b   = blockIdx.x / BLOCKS_PER_BATCH;
    const int blk = blockIdx.x % BLOCKS_PER_BATCH;

    const float4* __restrict__ x4 = reinterpret_cast<const float4*>(x   + (size_t)b * N_PER_BATCH);
    const float4* __restrict__ i4 = reinterpret_cast<const float4*>(inp + (size_t)b * N_PER_BATCH);
    const int n4 = (int)(N_PER_BATCH / 4);                 // 983,040

    float acc = 0.0f;
    for (int i = blk * THREADS + threadIdx.x; i < n4; i += BLOCKS_PER_BATCH * THREADS) {
        float4 xv = x4[i];
        float4 iv = i4[i];
        float d0 = iv.x - xv.x;
        float d1 = iv.y - xv.y;
        float d2 = iv.z - xv.z;
        float d3 = iv.w - xv.w;
        acc += isfinite(iv.x) ? d0 * d0 : 0.0f;
        acc += isfinite(iv.y) ? d1 * d1 : 0.0f;
        acc += isfinite(iv.z) ? d2 * d2 : 0.0f;
        acc += isfinite(iv.w) ? d3 * d3 : 0.0f;
    }

    // wave reduce, then LDS across the block's 4 waves
    acc = wave_reduce_add(acc);
    __shared__ float lds[THREADS / 64];
    const int lane = threadIdx.x & 63;
    const int wave = threadIdx.x >> 6;
    if (lane == 0) lds[wave] = acc;
    __syncthreads();
    if (threadIdx.x == 0) {
        float s = 0.0f;
        #pragma unroll
        for (int w = 0; w < THREADS / 64; ++w) s += lds[w];
        partial[blockIdx.x] = s;                           // index == b*BLOCKS_PER_BATCH + blk
    }
}

__global__ __launch_bounds__(THREADS)
void nlpobs_final(const float* __restrict__ partial,
                  float* __restrict__ out) {
    const int b = blockIdx.x;                              // one block per batch
    float acc = partial[b * BLOCKS_PER_BATCH + threadIdx.x];
    acc = wave_reduce_add(acc);
    __shared__ float lds[THREADS / 64];
    const int lane = threadIdx.x & 63;
    const int wave = threadIdx.x >> 6;
    if (lane == 0) lds[wave] = acc;
    __syncthreads();
    if (threadIdx.x == 0) {
        float s = 0.0f;
        #pragma unroll
        for (int w = 0; w < THREADS / 64; ++w) s += lds[w];
        out[b] = NEG_INV_NOISE * s;
    }
}

extern "C" void kernel_launch(void* const* d_in, const int* in_sizes, int n_in,
                              void* d_out, int out_size, void* d_ws, size_t ws_size,
                              hipStream_t stream) {
    const float* x   = (const float*)d_in[0];
    const float* inp = (const float*)d_in[1];
    float* out       = (float*)d_out;
    float* partial   = (float*)d_ws;                        // needs 8*256*4 = 8 KB

    nlpobs_partial<<<N_B * BLOCKS_PER_BATCH, THREADS, 0, stream>>>(x, inp, partial);
    nlpobs_final<<<N_B, THREADS, 0, stream>>>(partial, out);
}